// Round 6
// baseline (219.657 us; speedup 1.0000x reference)
//
#include <hip/hip_runtime.h>
#include <hip/hip_bf16.h>

// Two pairwise MLPs (ChG, DG) over 1024x1024 pairs, then A_chg @ A_gd, sigmoid.
// Outputs concat: [0:1M) sigmoid(A_chd), [1M:2M) A_chg, [2M:3M) A_gd (fp32).
//
// R6 (= R5 with compile fix): transposed hidden GEMM h1^T = W1^T @ h^T.
// W1^T lives in the A operand (constant regs), h in the B operand. C-layout
// gives pair=col=lane&15, n=row=quad*4+r, so Dense(1) is an in-lane 16-FMA
// dot + TWO shfl_xor (16,32) instead of a 16-shfl butterfly. hl is
// wave-uniform -> read straight from global (L1 broadcast), no LDS staging,
// no barriers in the l-loop. br1's AgdT fp16 copy goes via a 4KB LDS
// transpose buffer. prep = precompute_hlr + pack_w1 fused.
// (R5 failed: __hmax2 resolves to the bf16 overload when hip_bf16.h is
// included -> relu via fp32 fmaxf before cvt_pkrtz, as in R4.)

typedef _Float16 half8 __attribute__((ext_vector_type(8)));
typedef __fp16 fp16x2 __attribute__((ext_vector_type(2)));
typedef float floatx4 __attribute__((ext_vector_type(4)));

union U4H8 { uint4 u; half8 h; };
union PH { fp16x2 c; unsigned int u; };

// ---------------------------------------------------------------- prep
// blocks 0..2047: wsf (floats): seg0 HL_chg(+b0c), seg1 HR_chg,
//                 seg2 HL_dg(+b0d), seg3 HR_dg; each [1024][128]
// blocks 2048..2111: w1frag[br][f=mt*4+ks][lane][j] =
//                 f16( W1[ks*32+(lane>>4)*8+j][mt*16+(lane&15)] )  (A-layout of W1^T)
__global__ __launch_bounds__(256) void prep(
    const float* __restrict__ Xch, const float* __restrict__ Xg,
    const float* __restrict__ Xd,
    const float* __restrict__ Wc0, const float* __restrict__ bc0,
    const float* __restrict__ Wd0, const float* __restrict__ bd0,
    const float* __restrict__ W1c, const float* __restrict__ W1d,
    float* __restrict__ wsf, _Float16* __restrict__ w1frag)
{
    int bid = blockIdx.x;
    if (bid < 2048) {
        int t = bid * 256 + threadIdx.x;   // 524288 threads
        int seg = t >> 17;
        int i = (t >> 7) & 1023;
        int k = t & 127;
        const float* X;
        const float* W;
        float s = 0.f;
        int wo = 0;
        if (seg == 0)      { X = Xch; W = Wc0; s = bc0[k]; }
        else if (seg == 1) { X = Xg;  W = Wc0; wo = 5; }
        else if (seg == 2) { X = Xg;  W = Wd0; s = bd0[k]; }
        else               { X = Xd;  W = Wd0; wo = 5; }
#pragma unroll
        for (int j = 0; j < 5; ++j)
            s += X[i * 5 + j] * W[(wo + j) * 128 + k];
        wsf[t] = s;
    } else {
        int t = (bid - 2048) * 256 + threadIdx.x;   // 16384 threads
        int br   = t >> 13;
        int f    = (t >> 9) & 15;
        int lane = (t >> 3) & 63;
        int j    = t & 7;
        int mt = f >> 2, ks = f & 3;
        int row = ks * 32 + (lane >> 4) * 8 + j;    // k of W1
        int col = mt * 16 + (lane & 15);            // n of W1
        const float* W = br ? W1d : W1c;
        w1frag[t] = (_Float16)W[row * 64 + col];
    }
}

// ---------------------------------------------------------------- branch
#define LC 32

__global__ __launch_bounds__(256, 3) void branch_kernel(
    const float* __restrict__ wsf,
    const float* __restrict__ b1_chg, const float* __restrict__ wr_chg, const float* __restrict__ br_chg,
    const float* __restrict__ b1_dg,  const float* __restrict__ wr_dg,  const float* __restrict__ br_dg,
    const _Float16* __restrict__ w1frag,
    float* __restrict__ d_out,
    _Float16* __restrict__ wsh)   // [0:1M) Achg f16 [ch][g], [1M:2M) AgdT f16 [d][g]
{
    __shared__ _Float16 lds_t[64 * LC];   // br1 transpose buffer (4 KB)

    const int br = blockIdx.z;
    const float* HL = wsf + (br ? 262144 : 0);
    const float* HR = wsf + (br ? 393216 : 131072);
    const float* b1 = br ? b1_dg : b1_chg;
    const float* wr = br ? wr_dg : wr_chg;
    const float brv = br ? br_dg[0] : br_chg[0];
    float* outA = d_out + (br ? 2097152 : 1048576);
    _Float16* outB = wsh + (br ? 1048576 : 0);

    const int tid = threadIdx.x;
    const int lane = tid & 63, wave = tid >> 6;
    const int m = lane & 15, quad = lane >> 4;
    const int lbase = blockIdx.y * LC;
    const int rbase = blockIdx.x * 64;
    const int rm = rbase + wave * 16 + m;   // this lane's pair (column)

    // hr in B-frag k-order: k = ks*32 + quad*8 + j (fp32, stays in regs)
    float hr[4][8];
#pragma unroll
    for (int ks = 0; ks < 4; ++ks) {
        const floatx4* p = (const floatx4*)(HR + rm * 128 + ks * 32 + quad * 8);
        floatx4 v0 = p[0], v1 = p[1];
#pragma unroll
        for (int j = 0; j < 4; ++j) { hr[ks][j] = v0[j]; hr[ks][4 + j] = v1[j]; }
    }

    // W1^T A-fragments (constant across the loop)
    half8 w1f[4][4];   // [mt][ks]
    {
        const uint4* wf = (const uint4*)(w1frag + br * 8192);
#pragma unroll
        for (int f = 0; f < 16; ++f) {
            U4H8 t; t.u = wf[f * 64 + lane];
            w1f[f >> 2][f & 3] = t.h;
        }
    }

    // per-lane n-slice constants: n = mt*16 + quad*4 + r
    floatx4 b1q[4], wrq[4];
#pragma unroll
    for (int mt = 0; mt < 4; ++mt) {
        b1q[mt] = *(const floatx4*)(b1 + mt * 16 + quad * 4);
        wrq[mt] = *(const floatx4*)(wr + mt * 16 + quad * 4);
    }

    for (int li = 0; li < LC; ++li) {
        const int l = lbase + li;
        const float* hlp = HL + l * 128;

        // h = relu(hl + hr) -> fp16 B-fragments (fp32 fmaxf, then pkrtz)
        half8 bfr[4];
#pragma unroll
        for (int ks = 0; ks < 4; ++ks) {
            const floatx4* p = (const floatx4*)(hlp + ks * 32 + quad * 8);
            floatx4 h0 = p[0], h1 = p[1];
            float v0 = fmaxf(h0[0] + hr[ks][0], 0.f);
            float v1 = fmaxf(h0[1] + hr[ks][1], 0.f);
            float v2 = fmaxf(h0[2] + hr[ks][2], 0.f);
            float v3 = fmaxf(h0[3] + hr[ks][3], 0.f);
            float v4 = fmaxf(h1[0] + hr[ks][4], 0.f);
            float v5 = fmaxf(h1[1] + hr[ks][5], 0.f);
            float v6 = fmaxf(h1[2] + hr[ks][6], 0.f);
            float v7 = fmaxf(h1[3] + hr[ks][7], 0.f);
            PH c0, c1, c2, c3;
            c0.c = __builtin_amdgcn_cvt_pkrtz(v0, v1);
            c1.c = __builtin_amdgcn_cvt_pkrtz(v2, v3);
            c2.c = __builtin_amdgcn_cvt_pkrtz(v4, v5);
            c3.c = __builtin_amdgcn_cvt_pkrtz(v6, v7);
            U4H8 t; t.u = make_uint4(c0.u, c1.u, c2.u, c3.u);
            bfr[ks] = t.h;
        }

        floatx4 acc[4];
#pragma unroll
        for (int mt = 0; mt < 4; ++mt)
            acc[mt] = (floatx4){0.f, 0.f, 0.f, 0.f};
#pragma unroll
        for (int ks = 0; ks < 4; ++ks)
#pragma unroll
            for (int mt = 0; mt < 4; ++mt)
                acc[mt] = __builtin_amdgcn_mfma_f32_16x16x32_f16(w1f[mt][ks], bfr[ks], acc[mt], 0, 0, 0);

        // acc[mt][r] = h1[pair rm][n = mt*16 + quad*4 + r]
        float y = 0.f;
#pragma unroll
        for (int mt = 0; mt < 4; ++mt)
#pragma unroll
            for (int r = 0; r < 4; ++r)
                y += fmaxf(acc[mt][r] + b1q[mt][r], 0.f) * wrq[mt][r];

        y += __shfl_xor(y, 16, 64);
        y += __shfl_xor(y, 32, 64);

        if (quad == 0) {
            float v = y + brv;
            float A = v > 0.f ? v : (expf(v) - 1.f);   // elu
            outA[l * 1024 + rm] = A;
            if (br == 0)
                outB[l * 1024 + rm] = (_Float16)A;          // Achg [ch][g]
            else
                lds_t[(wave * 16 + m) * LC + li] = (_Float16)A;   // stage for transpose
        }
    }

    if (br == 1) {   // write AgdT [d][g] tiles, coalesced
        __syncthreads();
        int r = tid >> 2, seg = tid & 3;
        *(uint4*)(outB + (rbase + r) * 1024 + lbase + seg * 8) =
            *(const uint4*)(lds_t + r * LC + seg * 8);
    }
}

// ---------------------------------------------------------------- final GEMM + sigmoid
// C[ch][d] = sum_g Achg[ch][g]*Agd[g][d]; fp16 MFMA, fp32 accum, reg-prefetch.
__global__ __launch_bounds__(256) void gemm_sig(
    const _Float16* __restrict__ Ahf,   // [1024][1024] ch x g
    const _Float16* __restrict__ BThf,  // [1024][1024] d x g
    float* __restrict__ out0)
{
    __shared__ _Float16 At[64 * 72];   // +8 pad
    __shared__ _Float16 Bt[64 * 72];

    const int tid = threadIdx.x, lane = tid & 63, wave = tid >> 6;
    const int m = lane & 15, quad = lane >> 4;
    const int chbase = blockIdx.y * 64, dbase = blockIdx.x * 64;
    const int wrow = (wave >> 1) * 32, wcol = (wave & 1) * 32;

    floatx4 acc[2][2];
#pragma unroll
    for (int mi = 0; mi < 2; ++mi)
#pragma unroll
        for (int ni = 0; ni < 2; ++ni)
            acc[mi][ni] = (floatx4){0.f, 0.f, 0.f, 0.f};

    uint4 ra[2], rb[2];
#pragma unroll
    for (int i = 0; i < 2; ++i) {
        int idx = tid + i * 256, rr = idx >> 3, cc = idx & 7;
        ra[i] = *(const uint4*)(Ahf + (chbase + rr) * 1024 + cc * 8);
        rb[i] = *(const uint4*)(BThf + (dbase + rr) * 1024 + cc * 8);
    }

    for (int kb = 0; kb < 1024; kb += 64) {
#pragma unroll
        for (int i = 0; i < 2; ++i) {
            int idx = tid + i * 256, rr = idx >> 3, cc = idx & 7;
            *(uint4*)(At + rr * 72 + cc * 8) = ra[i];
            *(uint4*)(Bt + rr * 72 + cc * 8) = rb[i];
        }
        __syncthreads();
        if (kb + 64 < 1024) {
#pragma unroll
            for (int i = 0; i < 2; ++i) {
                int idx = tid + i * 256, rr = idx >> 3, cc = idx & 7;
                ra[i] = *(const uint4*)(Ahf + (chbase + rr) * 1024 + kb + 64 + cc * 8);
                rb[i] = *(const uint4*)(BThf + (dbase + rr) * 1024 + kb + 64 + cc * 8);
            }
        }
#pragma unroll
        for (int k2 = 0; k2 < 2; ++k2) {
            int koff = k2 * 32 + quad * 8;
            half8 a[2], b[2];
            a[0] = *(const half8*)(At + (wrow + m) * 72 + koff);
            a[1] = *(const half8*)(At + (wrow + 16 + m) * 72 + koff);
            b[0] = *(const half8*)(Bt + (wcol + m) * 72 + koff);
            b[1] = *(const half8*)(Bt + (wcol + 16 + m) * 72 + koff);
#pragma unroll
            for (int mi = 0; mi < 2; ++mi)
#pragma unroll
                for (int ni = 0; ni < 2; ++ni)
                    acc[mi][ni] = __builtin_amdgcn_mfma_f32_16x16x32_f16(a[mi], b[ni], acc[mi][ni], 0, 0, 0);
        }
        __syncthreads();
    }

#pragma unroll
    for (int mi = 0; mi < 2; ++mi)
#pragma unroll
        for (int ni = 0; ni < 2; ++ni)
#pragma unroll
            for (int r = 0; r < 4; ++r) {
                int row = chbase + wrow + mi * 16 + quad * 4 + r;
                int col = dbase + wcol + ni * 16 + m;
                float v = acc[mi][ni][r];
                out0[row * 1024 + col] = 1.f / (1.f + expf(-v));
            }
}

// ---------------------------------------------------------------- launch
extern "C" void kernel_launch(void* const* d_in, const int* in_sizes, int n_in,
                              void* d_out, int out_size, void* d_ws, size_t ws_size,
                              hipStream_t stream) {
    const float* Xch = (const float*)d_in[0];
    const float* Xg  = (const float*)d_in[1];
    const float* Xd  = (const float*)d_in[2];
    const float* Wc0 = (const float*)d_in[3];
    const float* bc0 = (const float*)d_in[4];
    const float* Wc1 = (const float*)d_in[5];
    const float* bc1 = (const float*)d_in[6];
    const float* Wcr = (const float*)d_in[7];
    const float* bcr = (const float*)d_in[8];
    const float* Wd0 = (const float*)d_in[9];
    const float* bd0 = (const float*)d_in[10];
    const float* Wd1 = (const float*)d_in[11];
    const float* bd1 = (const float*)d_in[12];
    const float* Wdr = (const float*)d_in[13];
    const float* bdr = (const float*)d_in[14];

    float* out = (float*)d_out;
    float* wsf = (float*)d_ws;                           // 4x1024x128 fp32 = 2 MB
    _Float16* wsh = (_Float16*)(wsf + 524288);           // Achg f16 1M + AgdT f16 1M
    _Float16* w1frag = wsh + 2097152;                    // 16384 f16

    prep<<<2112, 256, 0, stream>>>(Xch, Xg, Xd, Wc0, bc0, Wd0, bd0, Wc1, Wd1,
                                   wsf, w1frag);

    dim3 gb(16, 32, 2);   // (r-chunks of 64, l-chunks of 32, branch)
    branch_kernel<<<gb, 256, 0, stream>>>(wsf, bc1, Wcr, bcr, bd1, Wdr, bdr,
                                          w1frag, out, wsh);

    dim3 gg(16, 16);
    gemm_sig<<<gg, 256, 0, stream>>>(wsh, wsh + 1048576, out);
}

// Round 7
// 165.904 us; speedup vs baseline: 1.3240x; 1.3240x over previous
//
#include <hip/hip_runtime.h>
#include <hip/hip_bf16.h>

// Two pairwise MLPs (ChG, DG) over 1024x1024 pairs, then A_chg @ A_gd, sigmoid.
// Outputs concat: [0:1M) sigmoid(A_chd), [1M:2M) A_chg, [2M:3M) A_gd (fp32).
//
// R7 = R6's transposed hidden GEMM (h1^T = W1^T @ h^T: W1^T in A operand,
// h in B operand, Dense(1) = in-lane 16-FMA + 2 shfl_xor) **plus** R4's LDS
// staging of the hl tile (R6 read hl per-iteration from global: ~200cy vmcnt
// stall in the serial chain -> both pipes idle, 111us). lds_t transpose
// buffer padded to stride 40 halfwords (was 32: 8-way bank conflicts,
// SQ_LDS_BANK_CONFLICT=459k -> ~0).

typedef _Float16 half8 __attribute__((ext_vector_type(8)));
typedef __fp16 fp16x2 __attribute__((ext_vector_type(2)));
typedef float floatx4 __attribute__((ext_vector_type(4)));

union U4H8 { uint4 u; half8 h; };
union PH { fp16x2 c; unsigned int u; };

// ---------------------------------------------------------------- prep
// blocks 0..2047: wsf (floats): seg0 HL_chg(+b0c), seg1 HR_chg,
//                 seg2 HL_dg(+b0d), seg3 HR_dg; each [1024][128]
// blocks 2048..2111: w1frag[br][f=mt*4+ks][lane][j] =
//                 f16( W1[ks*32+(lane>>4)*8+j][mt*16+(lane&15)] )  (A-layout of W1^T)
__global__ __launch_bounds__(256) void prep(
    const float* __restrict__ Xch, const float* __restrict__ Xg,
    const float* __restrict__ Xd,
    const float* __restrict__ Wc0, const float* __restrict__ bc0,
    const float* __restrict__ Wd0, const float* __restrict__ bd0,
    const float* __restrict__ W1c, const float* __restrict__ W1d,
    float* __restrict__ wsf, _Float16* __restrict__ w1frag)
{
    int bid = blockIdx.x;
    if (bid < 2048) {
        int t = bid * 256 + threadIdx.x;   // 524288 threads
        int seg = t >> 17;
        int i = (t >> 7) & 1023;
        int k = t & 127;
        const float* X;
        const float* W;
        float s = 0.f;
        int wo = 0;
        if (seg == 0)      { X = Xch; W = Wc0; s = bc0[k]; }
        else if (seg == 1) { X = Xg;  W = Wc0; wo = 5; }
        else if (seg == 2) { X = Xg;  W = Wd0; s = bd0[k]; }
        else               { X = Xd;  W = Wd0; wo = 5; }
#pragma unroll
        for (int j = 0; j < 5; ++j)
            s += X[i * 5 + j] * W[(wo + j) * 128 + k];
        wsf[t] = s;
    } else {
        int t = (bid - 2048) * 256 + threadIdx.x;   // 16384 threads
        int br   = t >> 13;
        int f    = (t >> 9) & 15;
        int lane = (t >> 3) & 63;
        int j    = t & 7;
        int mt = f >> 2, ks = f & 3;
        int row = ks * 32 + (lane >> 4) * 8 + j;    // k of W1
        int col = mt * 16 + (lane & 15);            // n of W1
        const float* W = br ? W1d : W1c;
        w1frag[t] = (_Float16)W[row * 64 + col];
    }
}

// ---------------------------------------------------------------- branch
#define LC 32
#define TSTRIDE 40   // lds_t row stride in halfwords: m*20 mod 32 has period 8
                     // -> 2-way bank aliasing (free) instead of 8-way at 32

__global__ __launch_bounds__(256, 3) void branch_kernel(
    const float* __restrict__ wsf,
    const float* __restrict__ b1_chg, const float* __restrict__ wr_chg, const float* __restrict__ br_chg,
    const float* __restrict__ b1_dg,  const float* __restrict__ wr_dg,  const float* __restrict__ br_dg,
    const _Float16* __restrict__ w1frag,
    float* __restrict__ d_out,
    _Float16* __restrict__ wsh)   // [0:1M) Achg f16 [ch][g], [1M:2M) AgdT f16 [d][g]
{
    __shared__ float hl_tile[LC * 128];          // 16 KB
    __shared__ _Float16 lds_t[64 * TSTRIDE];     // br1 transpose buffer (5 KB)

    const int br = blockIdx.z;
    const float* HL = wsf + (br ? 262144 : 0);
    const float* HR = wsf + (br ? 393216 : 131072);
    const float* b1 = br ? b1_dg : b1_chg;
    const float* wr = br ? wr_dg : wr_chg;
    const float brv = br ? br_dg[0] : br_chg[0];
    float* outA = d_out + (br ? 2097152 : 1048576);
    _Float16* outB = wsh + (br ? 1048576 : 0);

    const int tid = threadIdx.x;
    const int lane = tid & 63, wave = tid >> 6;
    const int m = lane & 15, quad = lane >> 4;
    const int lbase = blockIdx.y * LC;
    const int rbase = blockIdx.x * 64;
    const int rm = rbase + wave * 16 + m;   // this lane's pair (column)

    {   // stage hl tile (fp32, b0 folded): LC*128 floats = 1024 float4
        const float4* src = (const float4*)(HL + lbase * 128);
        float4* dst = (float4*)hl_tile;
#pragma unroll
        for (int i = 0; i < (LC * 128 / 4) / 256; ++i)
            dst[tid + i * 256] = src[tid + i * 256];
    }

    // hr in B-frag k-order: k = ks*32 + quad*8 + j (fp32, stays in regs)
    float hr[4][8];
#pragma unroll
    for (int ks = 0; ks < 4; ++ks) {
        const floatx4* p = (const floatx4*)(HR + rm * 128 + ks * 32 + quad * 8);
        floatx4 v0 = p[0], v1 = p[1];
#pragma unroll
        for (int j = 0; j < 4; ++j) { hr[ks][j] = v0[j]; hr[ks][4 + j] = v1[j]; }
    }

    // W1^T A-fragments (constant across the loop)
    half8 w1f[4][4];   // [mt][ks]
    {
        const uint4* wf = (const uint4*)(w1frag + br * 8192);
#pragma unroll
        for (int f = 0; f < 16; ++f) {
            U4H8 t; t.u = wf[f * 64 + lane];
            w1f[f >> 2][f & 3] = t.h;
        }
    }

    // per-lane n-slice constants: n = mt*16 + quad*4 + r
    floatx4 b1q[4], wrq[4];
#pragma unroll
    for (int mt = 0; mt < 4; ++mt) {
        b1q[mt] = *(const floatx4*)(b1 + mt * 16 + quad * 4);
        wrq[mt] = *(const floatx4*)(wr + mt * 16 + quad * 4);
    }

    __syncthreads();

    for (int li = 0; li < LC; ++li) {
        const float* hlp = hl_tile + li * 128;

        // h = relu(hl + hr) -> fp16 B-fragments (fp32 fmaxf, then pkrtz)
        // LDS reads: quad q hits bank group q*8..q*8+7, 16-lane broadcast
        half8 bfr[4];
#pragma unroll
        for (int ks = 0; ks < 4; ++ks) {
            const floatx4* p = (const floatx4*)(hlp + ks * 32 + quad * 8);
            floatx4 h0 = p[0], h1 = p[1];
            float v0 = fmaxf(h0[0] + hr[ks][0], 0.f);
            float v1 = fmaxf(h0[1] + hr[ks][1], 0.f);
            float v2 = fmaxf(h0[2] + hr[ks][2], 0.f);
            float v3 = fmaxf(h0[3] + hr[ks][3], 0.f);
            float v4 = fmaxf(h1[0] + hr[ks][4], 0.f);
            float v5 = fmaxf(h1[1] + hr[ks][5], 0.f);
            float v6 = fmaxf(h1[2] + hr[ks][6], 0.f);
            float v7 = fmaxf(h1[3] + hr[ks][7], 0.f);
            PH c0, c1, c2, c3;
            c0.c = __builtin_amdgcn_cvt_pkrtz(v0, v1);
            c1.c = __builtin_amdgcn_cvt_pkrtz(v2, v3);
            c2.c = __builtin_amdgcn_cvt_pkrtz(v4, v5);
            c3.c = __builtin_amdgcn_cvt_pkrtz(v6, v7);
            U4H8 t; t.u = make_uint4(c0.u, c1.u, c2.u, c3.u);
            bfr[ks] = t.h;
        }

        floatx4 acc[4];
#pragma unroll
        for (int mt = 0; mt < 4; ++mt)
            acc[mt] = (floatx4){0.f, 0.f, 0.f, 0.f};
#pragma unroll
        for (int ks = 0; ks < 4; ++ks)
#pragma unroll
            for (int mt = 0; mt < 4; ++mt)
                acc[mt] = __builtin_amdgcn_mfma_f32_16x16x32_f16(w1f[mt][ks], bfr[ks], acc[mt], 0, 0, 0);

        // acc[mt][r] = h1[pair rm][n = mt*16 + quad*4 + r]
        float y = 0.f;
#pragma unroll
        for (int mt = 0; mt < 4; ++mt)
#pragma unroll
            for (int r = 0; r < 4; ++r)
                y += fmaxf(acc[mt][r] + b1q[mt][r], 0.f) * wrq[mt][r];

        y += __shfl_xor(y, 16, 64);
        y += __shfl_xor(y, 32, 64);

        if (quad == 0) {
            float v = y + brv;
            float A = v > 0.f ? v : (expf(v) - 1.f);   // elu
            const int l = lbase + li;
            outA[l * 1024 + rm] = A;
            if (br == 0)
                outB[l * 1024 + rm] = (_Float16)A;          // Achg [ch][g]
            else
                lds_t[(wave * 16 + m) * TSTRIDE + li] = (_Float16)A;   // stage
        }
    }

    if (br == 1) {   // write AgdT [d][g] tiles, coalesced
        __syncthreads();
        int r = tid >> 2, seg = tid & 3;
        *(uint4*)(outB + (rbase + r) * 1024 + lbase + seg * 8) =
            *(const uint4*)(lds_t + r * TSTRIDE + seg * 8);
    }
}

// ---------------------------------------------------------------- final GEMM + sigmoid
// C[ch][d] = sum_g Achg[ch][g]*Agd[g][d]; fp16 MFMA, fp32 accum, reg-prefetch.
__global__ __launch_bounds__(256) void gemm_sig(
    const _Float16* __restrict__ Ahf,   // [1024][1024] ch x g
    const _Float16* __restrict__ BThf,  // [1024][1024] d x g
    float* __restrict__ out0)
{
    __shared__ _Float16 At[64 * 72];   // +8 pad
    __shared__ _Float16 Bt[64 * 72];

    const int tid = threadIdx.x, lane = tid & 63, wave = tid >> 6;
    const int m = lane & 15, quad = lane >> 4;
    const int chbase = blockIdx.y * 64, dbase = blockIdx.x * 64;
    const int wrow = (wave >> 1) * 32, wcol = (wave & 1) * 32;

    floatx4 acc[2][2];
#pragma unroll
    for (int mi = 0; mi < 2; ++mi)
#pragma unroll
        for (int ni = 0; ni < 2; ++ni)
            acc[mi][ni] = (floatx4){0.f, 0.f, 0.f, 0.f};

    uint4 ra[2], rb[2];
#pragma unroll
    for (int i = 0; i < 2; ++i) {
        int idx = tid + i * 256, rr = idx >> 3, cc = idx & 7;
        ra[i] = *(const uint4*)(Ahf + (chbase + rr) * 1024 + cc * 8);
        rb[i] = *(const uint4*)(BThf + (dbase + rr) * 1024 + cc * 8);
    }

    for (int kb = 0; kb < 1024; kb += 64) {
#pragma unroll
        for (int i = 0; i < 2; ++i) {
            int idx = tid + i * 256, rr = idx >> 3, cc = idx & 7;
            *(uint4*)(At + rr * 72 + cc * 8) = ra[i];
            *(uint4*)(Bt + rr * 72 + cc * 8) = rb[i];
        }
        __syncthreads();
        if (kb + 64 < 1024) {
#pragma unroll
            for (int i = 0; i < 2; ++i) {
                int idx = tid + i * 256, rr = idx >> 3, cc = idx & 7;
                ra[i] = *(const uint4*)(Ahf + (chbase + rr) * 1024 + kb + 64 + cc * 8);
                rb[i] = *(const uint4*)(BThf + (dbase + rr) * 1024 + kb + 64 + cc * 8);
            }
        }
#pragma unroll
        for (int k2 = 0; k2 < 2; ++k2) {
            int koff = k2 * 32 + quad * 8;
            half8 a[2], b[2];
            a[0] = *(const half8*)(At + (wrow + m) * 72 + koff);
            a[1] = *(const half8*)(At + (wrow + 16 + m) * 72 + koff);
            b[0] = *(const half8*)(Bt + (wcol + m) * 72 + koff);
            b[1] = *(const half8*)(Bt + (wcol + 16 + m) * 72 + koff);
#pragma unroll
            for (int mi = 0; mi < 2; ++mi)
#pragma unroll
                for (int ni = 0; ni < 2; ++ni)
                    acc[mi][ni] = __builtin_amdgcn_mfma_f32_16x16x32_f16(a[mi], b[ni], acc[mi][ni], 0, 0, 0);
        }
        __syncthreads();
    }

#pragma unroll
    for (int mi = 0; mi < 2; ++mi)
#pragma unroll
        for (int ni = 0; ni < 2; ++ni)
#pragma unroll
            for (int r = 0; r < 4; ++r) {
                int row = chbase + wrow + mi * 16 + quad * 4 + r;
                int col = dbase + wcol + ni * 16 + m;
                float v = acc[mi][ni][r];
                out0[row * 1024 + col] = 1.f / (1.f + expf(-v));
            }
}

// ---------------------------------------------------------------- launch
extern "C" void kernel_launch(void* const* d_in, const int* in_sizes, int n_in,
                              void* d_out, int out_size, void* d_ws, size_t ws_size,
                              hipStream_t stream) {
    const float* Xch = (const float*)d_in[0];
    const float* Xg  = (const float*)d_in[1];
    const float* Xd  = (const float*)d_in[2];
    const float* Wc0 = (const float*)d_in[3];
    const float* bc0 = (const float*)d_in[4];
    const float* Wc1 = (const float*)d_in[5];
    const float* bc1 = (const float*)d_in[6];
    const float* Wcr = (const float*)d_in[7];
    const float* bcr = (const float*)d_in[8];
    const float* Wd0 = (const float*)d_in[9];
    const float* bd0 = (const float*)d_in[10];
    const float* Wd1 = (const float*)d_in[11];
    const float* bd1 = (const float*)d_in[12];
    const float* Wdr = (const float*)d_in[13];
    const float* bdr = (const float*)d_in[14];

    float* out = (float*)d_out;
    float* wsf = (float*)d_ws;                           // 4x1024x128 fp32 = 2 MB
    _Float16* wsh = (_Float16*)(wsf + 524288);           // Achg f16 1M + AgdT f16 1M
    _Float16* w1frag = wsh + 2097152;                    // 16384 f16

    prep<<<2112, 256, 0, stream>>>(Xch, Xg, Xd, Wc0, bc0, Wd0, bd0, Wc1, Wd1,
                                   wsf, w1frag);

    dim3 gb(16, 32, 2);   // (r-chunks of 64, l-chunks of 32, branch)
    branch_kernel<<<gb, 256, 0, stream>>>(wsf, bc1, Wcr, bcr, bd1, Wdr, bdr,
                                          w1frag, out, wsh);

    dim3 gg(16, 16);
    gemm_sig<<<gg, 256, 0, stream>>>(wsh, wsh + 1048576, out);
}

// Round 8
// 150.269 us; speedup vs baseline: 1.4618x; 1.1040x over previous
//
#include <hip/hip_runtime.h>
#include <hip/hip_bf16.h>

// Two pairwise MLPs (ChG, DG) over 1024x1024 pairs, then A_chg @ A_gd, sigmoid.
// Outputs concat: [0:1M) sigmoid(A_chd), [1M:2M) A_chg, [2M:3M) A_gd (fp32).
//
// R8 = R7 + three bit-identical-numerics optimizations:
//  1. b1 folded into MFMA acc init (acc = b1 instead of 0; epilogue drops 16 adds).
//  2. float2-packed fp32 math in h-gen + epilogue -> v_pk_add_f32/v_pk_fma_f32
//     (2 fp32 ops per inst on CDNA4; falls back to scalar at worst).
//  3. gemm_sig retiled 64x64 -> 32x32 (grid 256 -> 1024 blocks = 4/CU): the
//     single dependent MFMA acc chain is latency-bound, needs occupancy.

typedef _Float16 half8 __attribute__((ext_vector_type(8)));
typedef __fp16 fp16x2 __attribute__((ext_vector_type(2)));
typedef float floatx4 __attribute__((ext_vector_type(4)));
typedef float floatx2 __attribute__((ext_vector_type(2)));

union U4H8 { uint4 u; half8 h; };
union PH { fp16x2 c; unsigned int u; };

// ---------------------------------------------------------------- prep
// blocks 0..2047: wsf (floats): seg0 HL_chg(+b0c), seg1 HR_chg,
//                 seg2 HL_dg(+b0d), seg3 HR_dg; each [1024][128]
// blocks 2048..2111: w1frag[br][f=mt*4+ks][lane][j] =
//                 f16( W1[ks*32+(lane>>4)*8+j][mt*16+(lane&15)] )  (A-layout of W1^T)
__global__ __launch_bounds__(256) void prep(
    const float* __restrict__ Xch, const float* __restrict__ Xg,
    const float* __restrict__ Xd,
    const float* __restrict__ Wc0, const float* __restrict__ bc0,
    const float* __restrict__ Wd0, const float* __restrict__ bd0,
    const float* __restrict__ W1c, const float* __restrict__ W1d,
    float* __restrict__ wsf, _Float16* __restrict__ w1frag)
{
    int bid = blockIdx.x;
    if (bid < 2048) {
        int t = bid * 256 + threadIdx.x;   // 524288 threads
        int seg = t >> 17;
        int i = (t >> 7) & 1023;
        int k = t & 127;
        const float* X;
        const float* W;
        float s = 0.f;
        int wo = 0;
        if (seg == 0)      { X = Xch; W = Wc0; s = bc0[k]; }
        else if (seg == 1) { X = Xg;  W = Wc0; wo = 5; }
        else if (seg == 2) { X = Xg;  W = Wd0; s = bd0[k]; }
        else               { X = Xd;  W = Wd0; wo = 5; }
#pragma unroll
        for (int j = 0; j < 5; ++j)
            s += X[i * 5 + j] * W[(wo + j) * 128 + k];
        wsf[t] = s;
    } else {
        int t = (bid - 2048) * 256 + threadIdx.x;   // 16384 threads
        int br   = t >> 13;
        int f    = (t >> 9) & 15;
        int lane = (t >> 3) & 63;
        int j    = t & 7;
        int mt = f >> 2, ks = f & 3;
        int row = ks * 32 + (lane >> 4) * 8 + j;    // k of W1
        int col = mt * 16 + (lane & 15);            // n of W1
        const float* W = br ? W1d : W1c;
        w1frag[t] = (_Float16)W[row * 64 + col];
    }
}

// ---------------------------------------------------------------- branch
#define LC 32
#define TSTRIDE 40   // lds_t row stride in halfwords: 2-way bank aliasing (free)

__global__ __launch_bounds__(256, 3) void branch_kernel(
    const float* __restrict__ wsf,
    const float* __restrict__ b1_chg, const float* __restrict__ wr_chg, const float* __restrict__ br_chg,
    const float* __restrict__ b1_dg,  const float* __restrict__ wr_dg,  const float* __restrict__ br_dg,
    const _Float16* __restrict__ w1frag,
    float* __restrict__ d_out,
    _Float16* __restrict__ wsh)   // [0:1M) Achg f16 [ch][g], [1M:2M) AgdT f16 [d][g]
{
    __shared__ float hl_tile[LC * 128];          // 16 KB
    __shared__ _Float16 lds_t[64 * TSTRIDE];     // br1 transpose buffer (5 KB)

    const int br = blockIdx.z;
    const float* HL = wsf + (br ? 262144 : 0);
    const float* HR = wsf + (br ? 393216 : 131072);
    const float* b1 = br ? b1_dg : b1_chg;
    const float* wr = br ? wr_dg : wr_chg;
    const float brv = br ? br_dg[0] : br_chg[0];
    float* outA = d_out + (br ? 2097152 : 1048576);
    _Float16* outB = wsh + (br ? 1048576 : 0);

    const int tid = threadIdx.x;
    const int lane = tid & 63, wave = tid >> 6;
    const int m = lane & 15, quad = lane >> 4;
    const int lbase = blockIdx.y * LC;
    const int rbase = blockIdx.x * 64;
    const int rm = rbase + wave * 16 + m;   // this lane's pair (column)

    {   // stage hl tile (fp32, b0 folded): LC*128 floats = 1024 float4
        const float4* src = (const float4*)(HL + lbase * 128);
        float4* dst = (float4*)hl_tile;
#pragma unroll
        for (int i = 0; i < (LC * 128 / 4) / 256; ++i)
            dst[tid + i * 256] = src[tid + i * 256];
    }

    // hr in B-frag k-order as float2 pairs: k = ks*32 + quad*8 + 2*p + {0,1}
    floatx2 hr2[4][4];
#pragma unroll
    for (int ks = 0; ks < 4; ++ks) {
        const floatx4* p = (const floatx4*)(HR + rm * 128 + ks * 32 + quad * 8);
        floatx4 v0 = p[0], v1 = p[1];
        hr2[ks][0] = __builtin_shufflevector(v0, v0, 0, 1);
        hr2[ks][1] = __builtin_shufflevector(v0, v0, 2, 3);
        hr2[ks][2] = __builtin_shufflevector(v1, v1, 0, 1);
        hr2[ks][3] = __builtin_shufflevector(v1, v1, 2, 3);
    }

    // W1^T A-fragments (constant across the loop)
    half8 w1f[4][4];   // [mt][ks]
    {
        const uint4* wf = (const uint4*)(w1frag + br * 8192);
#pragma unroll
        for (int f = 0; f < 16; ++f) {
            U4H8 t; t.u = wf[f * 64 + lane];
            w1f[f >> 2][f & 3] = t.h;
        }
    }

    // per-lane n-slice constants: n = mt*16 + quad*4 + r
    floatx4 b1q[4];
    floatx2 wr2l[4], wr2h[4];
#pragma unroll
    for (int mt = 0; mt < 4; ++mt) {
        b1q[mt] = *(const floatx4*)(b1 + mt * 16 + quad * 4);
        floatx4 w4 = *(const floatx4*)(wr + mt * 16 + quad * 4);
        wr2l[mt] = __builtin_shufflevector(w4, w4, 0, 1);
        wr2h[mt] = __builtin_shufflevector(w4, w4, 2, 3);
    }

    const floatx2 z2 = (floatx2){0.f, 0.f};

    __syncthreads();

    for (int li = 0; li < LC; ++li) {
        const float* hlp = hl_tile + li * 128;

        // h = relu(hl + hr) -> fp16 B-fragments (pk_add_f32 + max + pkrtz)
        half8 bfr[4];
#pragma unroll
        for (int ks = 0; ks < 4; ++ks) {
            const floatx4* p = (const floatx4*)(hlp + ks * 32 + quad * 8);
            floatx4 h0 = p[0], h1 = p[1];
            floatx2 s0 = __builtin_shufflevector(h0, h0, 0, 1) + hr2[ks][0];
            floatx2 s1 = __builtin_shufflevector(h0, h0, 2, 3) + hr2[ks][1];
            floatx2 s2 = __builtin_shufflevector(h1, h1, 0, 1) + hr2[ks][2];
            floatx2 s3 = __builtin_shufflevector(h1, h1, 2, 3) + hr2[ks][3];
            s0 = __builtin_elementwise_max(s0, z2);
            s1 = __builtin_elementwise_max(s1, z2);
            s2 = __builtin_elementwise_max(s2, z2);
            s3 = __builtin_elementwise_max(s3, z2);
            PH c0, c1, c2, c3;
            c0.c = __builtin_amdgcn_cvt_pkrtz(s0[0], s0[1]);
            c1.c = __builtin_amdgcn_cvt_pkrtz(s1[0], s1[1]);
            c2.c = __builtin_amdgcn_cvt_pkrtz(s2[0], s2[1]);
            c3.c = __builtin_amdgcn_cvt_pkrtz(s3[0], s3[1]);
            U4H8 t; t.u = make_uint4(c0.u, c1.u, c2.u, c3.u);
            bfr[ks] = t.h;
        }

        floatx4 acc[4];
#pragma unroll
        for (int mt = 0; mt < 4; ++mt)
            acc[mt] = b1q[mt];   // b1 folded into the accumulator init
#pragma unroll
        for (int ks = 0; ks < 4; ++ks)
#pragma unroll
            for (int mt = 0; mt < 4; ++mt)
                acc[mt] = __builtin_amdgcn_mfma_f32_16x16x32_f16(w1f[mt][ks], bfr[ks], acc[mt], 0, 0, 0);

        // acc[mt][r] = h1[pair rm][n = mt*16+quad*4+r] + b1;  dot with Wr
        floatx2 y2 = z2;
#pragma unroll
        for (int mt = 0; mt < 4; ++mt) {
            floatx2 lo = __builtin_shufflevector(acc[mt], acc[mt], 0, 1);
            floatx2 hi = __builtin_shufflevector(acc[mt], acc[mt], 2, 3);
            y2 += __builtin_elementwise_max(lo, z2) * wr2l[mt];
            y2 += __builtin_elementwise_max(hi, z2) * wr2h[mt];
        }
        float y = y2[0] + y2[1];

        y += __shfl_xor(y, 16, 64);
        y += __shfl_xor(y, 32, 64);

        if (quad == 0) {
            float v = y + brv;
            float A = v > 0.f ? v : (expf(v) - 1.f);   // elu
            const int l = lbase + li;
            outA[l * 1024 + rm] = A;
            if (br == 0)
                outB[l * 1024 + rm] = (_Float16)A;          // Achg [ch][g]
            else
                lds_t[(wave * 16 + m) * TSTRIDE + li] = (_Float16)A;   // stage
        }
    }

    if (br == 1) {   // write AgdT [d][g] tiles, coalesced
        __syncthreads();
        int r = tid >> 2, seg = tid & 3;
        *(uint4*)(outB + (rbase + r) * 1024 + lbase + seg * 8) =
            *(const uint4*)(lds_t + r * TSTRIDE + seg * 8);
    }
}

// ---------------------------------------------------------------- final GEMM + sigmoid
// C[ch][d] = sum_g Achg[ch][g]*Agd[g][d]; fp16 MFMA, fp32 accum.
// 32x32 tiles, 1024 blocks (4/CU): the dependent acc chain is latency-bound,
// so buy occupancy instead of per-block tile size.
__global__ __launch_bounds__(256) void gemm_sig(
    const _Float16* __restrict__ Ahf,   // [1024][1024] ch x g
    const _Float16* __restrict__ BThf,  // [1024][1024] d x g
    float* __restrict__ out0)
{
    __shared__ _Float16 At[32 * 72];   // +8 pad
    __shared__ _Float16 Bt[32 * 72];

    const int tid = threadIdx.x, lane = tid & 63, wave = tid >> 6;
    const int m = lane & 15, quad = lane >> 4;
    const int chbase = blockIdx.y * 32, dbase = blockIdx.x * 32;
    const int wrow = (wave >> 1) * 16, wcol = (wave & 1) * 16;

    floatx4 acc = (floatx4){0.f, 0.f, 0.f, 0.f};

    const int row = tid >> 3, c4 = tid & 7;   // 32 rows x 8 uint4 = 256 threads
    uint4 ra = *(const uint4*)(Ahf + (chbase + row) * 1024 + c4 * 8);
    uint4 rb = *(const uint4*)(BThf + (dbase + row) * 1024 + c4 * 8);

    for (int kb = 0; kb < 1024; kb += 64) {
        *(uint4*)(At + row * 72 + c4 * 8) = ra;
        *(uint4*)(Bt + row * 72 + c4 * 8) = rb;
        __syncthreads();
        if (kb + 64 < 1024) {
            ra = *(const uint4*)(Ahf + (chbase + row) * 1024 + kb + 64 + c4 * 8);
            rb = *(const uint4*)(BThf + (dbase + row) * 1024 + kb + 64 + c4 * 8);
        }
#pragma unroll
        for (int k2 = 0; k2 < 2; ++k2) {
            int koff = k2 * 32 + quad * 8;
            half8 a = *(const half8*)(At + (wrow + m) * 72 + koff);
            half8 b = *(const half8*)(Bt + (wcol + m) * 72 + koff);
            acc = __builtin_amdgcn_mfma_f32_16x16x32_f16(a, b, acc, 0, 0, 0);
        }
        __syncthreads();
    }

#pragma unroll
    for (int r = 0; r < 4; ++r) {
        int row_o = chbase + wrow + quad * 4 + r;
        int col_o = dbase + wcol + m;
        out0[row_o * 1024 + col_o] = 1.f / (1.f + expf(-acc[r]));
    }
}

// ---------------------------------------------------------------- launch
extern "C" void kernel_launch(void* const* d_in, const int* in_sizes, int n_in,
                              void* d_out, int out_size, void* d_ws, size_t ws_size,
                              hipStream_t stream) {
    const float* Xch = (const float*)d_in[0];
    const float* Xg  = (const float*)d_in[1];
    const float* Xd  = (const float*)d_in[2];
    const float* Wc0 = (const float*)d_in[3];
    const float* bc0 = (const float*)d_in[4];
    const float* Wc1 = (const float*)d_in[5];
    const float* bc1 = (const float*)d_in[6];
    const float* Wcr = (const float*)d_in[7];
    const float* bcr = (const float*)d_in[8];
    const float* Wd0 = (const float*)d_in[9];
    const float* bd0 = (const float*)d_in[10];
    const float* Wd1 = (const float*)d_in[11];
    const float* bd1 = (const float*)d_in[12];
    const float* Wdr = (const float*)d_in[13];
    const float* bdr = (const float*)d_in[14];

    float* out = (float*)d_out;
    float* wsf = (float*)d_ws;                           // 4x1024x128 fp32 = 2 MB
    _Float16* wsh = (_Float16*)(wsf + 524288);           // Achg f16 1M + AgdT f16 1M
    _Float16* w1frag = wsh + 2097152;                    // 16384 f16

    prep<<<2112, 256, 0, stream>>>(Xch, Xg, Xd, Wc0, bc0, Wd0, bd0, Wc1, Wd1,
                                   wsf, w1frag);

    dim3 gb(16, 32, 2);   // (r-chunks of 64, l-chunks of 32, branch)
    branch_kernel<<<gb, 256, 0, stream>>>(wsf, bc1, Wcr, bcr, bd1, Wdr, bdr,
                                          w1frag, out, wsh);

    dim3 gg(32, 32);
    gemm_sig<<<gg, 256, 0, stream>>>(wsh, wsh + 1048576, out);
}

// Round 9
// 138.862 us; speedup vs baseline: 1.5818x; 1.0821x over previous
//
#include <hip/hip_runtime.h>
#include <hip/hip_bf16.h>

// Two pairwise MLPs (ChG, DG) over 1024x1024 pairs, then A_chg @ A_gd, sigmoid.
// Outputs concat: [0:1M) sigmoid(A_chd), [1M:2M) A_chg, [2M:3M) A_gd (fp32).
//
// R9 = R8 with a latency-bound fix (R8: VALU 52%, MFMA 22%, both pipes idle):
//  1. fp16 end-to-end h-path: HL/HR stored fp16 by prep; h = pk_max(pk_add(
//     hl16,hr16),0) in packed fp16 (v_pk_add_f16/v_pk_max_f16). Pack VALU
//     48->32 ops/iter, hl LDS reads 8->4 ds_read_b128, tile 16->8 KB.
//     Numerics: 3 roundings @2^-11 vs 1 (absmax ~0.03 expected, thr 0.0484).
//  2. #pragma unroll 2 on the l-loop: two independent pack/MFMA/dot chains
//     per wave to cover MFMA+DS latency.
//  3. gemm_sig dual accumulator (even/odd k2) for 2x MFMA ILP.

typedef _Float16 half8 __attribute__((ext_vector_type(8)));
typedef float floatx4 __attribute__((ext_vector_type(4)));
typedef float floatx2 __attribute__((ext_vector_type(2)));

union U4H8 { uint4 u; half8 h; };

// ---------------------------------------------------------------- prep
// blocks 0..2047: hlhr (fp16): seg0 HL_chg(+b0c), seg1 HR_chg,
//                 seg2 HL_dg(+b0d), seg3 HR_dg; each [1024][128]
// blocks 2048..2111: w1frag[br][f=mt*4+ks][lane][j] =
//                 f16( W1[ks*32+(lane>>4)*8+j][mt*16+(lane&15)] )  (A-layout of W1^T)
__global__ __launch_bounds__(256) void prep(
    const float* __restrict__ Xch, const float* __restrict__ Xg,
    const float* __restrict__ Xd,
    const float* __restrict__ Wc0, const float* __restrict__ bc0,
    const float* __restrict__ Wd0, const float* __restrict__ bd0,
    const float* __restrict__ W1c, const float* __restrict__ W1d,
    _Float16* __restrict__ hlhr, _Float16* __restrict__ w1frag)
{
    int bid = blockIdx.x;
    if (bid < 2048) {
        int t = bid * 256 + threadIdx.x;   // 524288 threads
        int seg = t >> 17;
        int i = (t >> 7) & 1023;
        int k = t & 127;
        const float* X;
        const float* W;
        float s = 0.f;
        int wo = 0;
        if (seg == 0)      { X = Xch; W = Wc0; s = bc0[k]; }
        else if (seg == 1) { X = Xg;  W = Wc0; wo = 5; }
        else if (seg == 2) { X = Xg;  W = Wd0; s = bd0[k]; }
        else               { X = Xd;  W = Wd0; wo = 5; }
#pragma unroll
        for (int j = 0; j < 5; ++j)
            s += X[i * 5 + j] * W[(wo + j) * 128 + k];
        hlhr[t] = (_Float16)s;   // fp32 dot, one RNE round to fp16
    } else {
        int t = (bid - 2048) * 256 + threadIdx.x;   // 16384 threads
        int br   = t >> 13;
        int f    = (t >> 9) & 15;
        int lane = (t >> 3) & 63;
        int j    = t & 7;
        int mt = f >> 2, ks = f & 3;
        int row = ks * 32 + (lane >> 4) * 8 + j;    // k of W1
        int col = mt * 16 + (lane & 15);            // n of W1
        const float* W = br ? W1d : W1c;
        w1frag[t] = (_Float16)W[row * 64 + col];
    }
}

// ---------------------------------------------------------------- branch
#define LC 32
#define TSTRIDE 40   // lds_t row stride in halfwords: 2-way bank aliasing (free)

__global__ __launch_bounds__(256, 3) void branch_kernel(
    const _Float16* __restrict__ hlhr,
    const float* __restrict__ b1_chg, const float* __restrict__ wr_chg, const float* __restrict__ br_chg,
    const float* __restrict__ b1_dg,  const float* __restrict__ wr_dg,  const float* __restrict__ br_dg,
    const _Float16* __restrict__ w1frag,
    float* __restrict__ d_out,
    _Float16* __restrict__ wsh)   // [0:1M) Achg f16 [ch][g], [1M:2M) AgdT f16 [d][g]
{
    __shared__ _Float16 hl_tile[LC * 128];       // 8 KB
    __shared__ _Float16 lds_t[64 * TSTRIDE];     // br1 transpose buffer (5 KB)

    const int br = blockIdx.z;
    const _Float16* HL = hlhr + (br ? 262144 : 0);
    const _Float16* HR = hlhr + (br ? 393216 : 131072);
    const float* b1 = br ? b1_dg : b1_chg;
    const float* wr = br ? wr_dg : wr_chg;
    const float brv = br ? br_dg[0] : br_chg[0];
    float* outA = d_out + (br ? 2097152 : 1048576);
    _Float16* outB = wsh + (br ? 1048576 : 0);

    const int tid = threadIdx.x;
    const int lane = tid & 63, wave = tid >> 6;
    const int m = lane & 15, quad = lane >> 4;
    const int lbase = blockIdx.y * LC;
    const int rbase = blockIdx.x * 64;
    const int rm = rbase + wave * 16 + m;   // this lane's pair (column)

    {   // stage hl tile (fp16, b0 folded): LC*128 halves = 512 uint4
        const uint4* src = (const uint4*)(HL + lbase * 128);
        uint4* dst = (uint4*)hl_tile;
#pragma unroll
        for (int i = 0; i < 2; ++i)
            dst[tid + i * 256] = src[tid + i * 256];
    }

    // hr in B-frag k-order (fp16): k = ks*32 + quad*8 + j
    half8 hr16[4];
#pragma unroll
    for (int ks = 0; ks < 4; ++ks)
        hr16[ks] = *(const half8*)(HR + rm * 128 + ks * 32 + quad * 8);

    // W1^T A-fragments (constant across the loop)
    half8 w1f[4][4];   // [mt][ks]
    {
        const uint4* wf = (const uint4*)(w1frag + br * 8192);
#pragma unroll
        for (int f = 0; f < 16; ++f) {
            U4H8 t; t.u = wf[f * 64 + lane];
            w1f[f >> 2][f & 3] = t.h;
        }
    }

    // per-lane n-slice constants: n = mt*16 + quad*4 + r
    floatx4 b1q[4];
    floatx2 wr2l[4], wr2h[4];
#pragma unroll
    for (int mt = 0; mt < 4; ++mt) {
        b1q[mt] = *(const floatx4*)(b1 + mt * 16 + quad * 4);
        floatx4 w4 = *(const floatx4*)(wr + mt * 16 + quad * 4);
        wr2l[mt] = __builtin_shufflevector(w4, w4, 0, 1);
        wr2h[mt] = __builtin_shufflevector(w4, w4, 2, 3);
    }

    const floatx2 z2 = (floatx2){0.f, 0.f};
    half8 hz;
#pragma unroll
    for (int j = 0; j < 8; ++j) hz[j] = (_Float16)0.f;

    __syncthreads();

#pragma unroll 2
    for (int li = 0; li < LC; ++li) {
        const _Float16* hlp = hl_tile + li * 128;

        // h = relu(hl16 + hr16) in packed fp16 -> B-fragments
        half8 bfr[4];
#pragma unroll
        for (int ks = 0; ks < 4; ++ks) {
            half8 hl8 = *(const half8*)(hlp + ks * 32 + quad * 8);
            bfr[ks] = __builtin_elementwise_max(hl8 + hr16[ks], hz);
        }

        floatx4 acc[4];
#pragma unroll
        for (int mt = 0; mt < 4; ++mt)
            acc[mt] = b1q[mt];   // b1 folded into the accumulator init
#pragma unroll
        for (int ks = 0; ks < 4; ++ks)
#pragma unroll
            for (int mt = 0; mt < 4; ++mt)
                acc[mt] = __builtin_amdgcn_mfma_f32_16x16x32_f16(w1f[mt][ks], bfr[ks], acc[mt], 0, 0, 0);

        // acc[mt][r] = h1[pair rm][n = mt*16+quad*4+r] + b1;  dot with Wr
        floatx2 y2 = z2;
#pragma unroll
        for (int mt = 0; mt < 4; ++mt) {
            floatx2 lo = __builtin_shufflevector(acc[mt], acc[mt], 0, 1);
            floatx2 hi = __builtin_shufflevector(acc[mt], acc[mt], 2, 3);
            y2 += __builtin_elementwise_max(lo, z2) * wr2l[mt];
            y2 += __builtin_elementwise_max(hi, z2) * wr2h[mt];
        }
        float y = y2[0] + y2[1];

        y += __shfl_xor(y, 16, 64);
        y += __shfl_xor(y, 32, 64);

        if (quad == 0) {
            float v = y + brv;
            float A = v > 0.f ? v : (expf(v) - 1.f);   // elu
            const int l = lbase + li;
            outA[l * 1024 + rm] = A;
            if (br == 0)
                outB[l * 1024 + rm] = (_Float16)A;          // Achg [ch][g]
            else
                lds_t[(wave * 16 + m) * TSTRIDE + li] = (_Float16)A;   // stage
        }
    }

    if (br == 1) {   // write AgdT [d][g] tiles, coalesced
        __syncthreads();
        int r = tid >> 2, seg = tid & 3;
        *(uint4*)(outB + (rbase + r) * 1024 + lbase + seg * 8) =
            *(const uint4*)(lds_t + r * TSTRIDE + seg * 8);
    }
}

// ---------------------------------------------------------------- final GEMM + sigmoid
// C[ch][d] = sum_g Achg[ch][g]*Agd[g][d]; fp16 MFMA, fp32 accum.
// 32x32 tiles, 1024 blocks (4/CU); dual accumulator for MFMA ILP.
__global__ __launch_bounds__(256) void gemm_sig(
    const _Float16* __restrict__ Ahf,   // [1024][1024] ch x g
    const _Float16* __restrict__ BThf,  // [1024][1024] d x g
    float* __restrict__ out0)
{
    __shared__ _Float16 At[32 * 72];   // +8 pad
    __shared__ _Float16 Bt[32 * 72];

    const int tid = threadIdx.x, lane = tid & 63, wave = tid >> 6;
    const int m = lane & 15, quad = lane >> 4;
    const int chbase = blockIdx.y * 32, dbase = blockIdx.x * 32;
    const int wrow = (wave >> 1) * 16, wcol = (wave & 1) * 16;

    floatx4 acc0 = (floatx4){0.f, 0.f, 0.f, 0.f};
    floatx4 acc1 = (floatx4){0.f, 0.f, 0.f, 0.f};

    const int row = tid >> 3, c4 = tid & 7;   // 32 rows x 8 uint4 = 256 threads
    uint4 ra = *(const uint4*)(Ahf + (chbase + row) * 1024 + c4 * 8);
    uint4 rb = *(const uint4*)(BThf + (dbase + row) * 1024 + c4 * 8);

    for (int kb = 0; kb < 1024; kb += 64) {
        *(uint4*)(At + row * 72 + c4 * 8) = ra;
        *(uint4*)(Bt + row * 72 + c4 * 8) = rb;
        __syncthreads();
        if (kb + 64 < 1024) {
            ra = *(const uint4*)(Ahf + (chbase + row) * 1024 + kb + 64 + c4 * 8);
            rb = *(const uint4*)(BThf + (dbase + row) * 1024 + kb + 64 + c4 * 8);
        }
        {
            half8 a0 = *(const half8*)(At + (wrow + m) * 72 + quad * 8);
            half8 b0 = *(const half8*)(Bt + (wcol + m) * 72 + quad * 8);
            half8 a1 = *(const half8*)(At + (wrow + m) * 72 + 32 + quad * 8);
            half8 b1 = *(const half8*)(Bt + (wcol + m) * 72 + 32 + quad * 8);
            acc0 = __builtin_amdgcn_mfma_f32_16x16x32_f16(a0, b0, acc0, 0, 0, 0);
            acc1 = __builtin_amdgcn_mfma_f32_16x16x32_f16(a1, b1, acc1, 0, 0, 0);
        }
        __syncthreads();
    }

    floatx4 acc = acc0 + acc1;
#pragma unroll
    for (int r = 0; r < 4; ++r) {
        int row_o = chbase + wrow + quad * 4 + r;
        int col_o = dbase + wcol + m;
        out0[row_o * 1024 + col_o] = 1.f / (1.f + expf(-acc[r]));
    }
}

// ---------------------------------------------------------------- launch
extern "C" void kernel_launch(void* const* d_in, const int* in_sizes, int n_in,
                              void* d_out, int out_size, void* d_ws, size_t ws_size,
                              hipStream_t stream) {
    const float* Xch = (const float*)d_in[0];
    const float* Xg  = (const float*)d_in[1];
    const float* Xd  = (const float*)d_in[2];
    const float* Wc0 = (const float*)d_in[3];
    const float* bc0 = (const float*)d_in[4];
    const float* Wc1 = (const float*)d_in[5];
    const float* bc1 = (const float*)d_in[6];
    const float* Wcr = (const float*)d_in[7];
    const float* bcr = (const float*)d_in[8];
    const float* Wd0 = (const float*)d_in[9];
    const float* bd0 = (const float*)d_in[10];
    const float* Wd1 = (const float*)d_in[11];
    const float* bd1 = (const float*)d_in[12];
    const float* Wdr = (const float*)d_in[13];
    const float* bdr = (const float*)d_in[14];

    float* out = (float*)d_out;
    _Float16* hlhr = (_Float16*)d_ws;            // 4x1024x128 fp16 = 1 MB
    _Float16* wsh = hlhr + 524288;               // Achg f16 1M + AgdT f16 1M
    _Float16* w1frag = wsh + 2097152;            // 16384 f16

    prep<<<2112, 256, 0, stream>>>(Xch, Xg, Xd, Wc0, bc0, Wd0, bd0, Wc1, Wd1,
                                   hlhr, w1frag);

    dim3 gb(16, 32, 2);   // (r-chunks of 64, l-chunks of 32, branch)
    branch_kernel<<<gb, 256, 0, stream>>>(hlhr, bc1, Wcr, bcr, bd1, Wdr, bdr,
                                          w1frag, out, wsh);

    dim3 gg(32, 32);
    gemm_sig<<<gg, 256, 0, stream>>>(wsh, wsh + 1048576, out);
}